// Round 1
// baseline (1539.438 us; speedup 1.0000x reference)
//
#include <hip/hip_runtime.h>
#include <hip/hip_bf16.h>

#define SCALE 0.07216878364870322f  // (3*64)^-0.5

// ---------------- K1: QKV projection ----------------
// per (b,c): [2048,256] @ [256,1536]^T -> Q/K/V in [bh][n][192] layout (dc = d*3+c)
// grid (32 n-tiles, 24 o-tiles, 6 bc), block 256
__global__ __launch_bounds__(256) void qkv_proj(const float* __restrict__ x,
                                                const float* __restrict__ w_qkv,
                                                float* __restrict__ Qb,
                                                float* __restrict__ Kb,
                                                float* __restrict__ Vb) {
    __shared__ float As[64][17];
    __shared__ float Bs[64][17];
    const int bc = blockIdx.z;
    const int b = bc / 3, c = bc % 3;
    const int o0 = blockIdx.y * 64;
    const int n0 = blockIdx.x * 64;
    const int tid = threadIdx.x;
    const int ty = tid >> 4, tx = tid & 15;
    float acc[4][4] = {};
    for (int k0 = 0; k0 < 256; k0 += 16) {
        __syncthreads();
        #pragma unroll
        for (int l = 0; l < 4; ++l) {
            int idx = tid + l * 256;
            int r = idx >> 4, kk = idx & 15;
            As[r][kk] = x[(((size_t)b * 2048 + n0 + r) * 256 + k0 + kk) * 3 + c];
            Bs[r][kk] = w_qkv[(size_t)(o0 + r) * 256 + k0 + kk];
        }
        __syncthreads();
        #pragma unroll
        for (int kk = 0; kk < 16; ++kk) {
            float a[4], bb[4];
            #pragma unroll
            for (int i = 0; i < 4; ++i) a[i] = As[ty * 4 + i][kk];
            #pragma unroll
            for (int j = 0; j < 4; ++j) bb[j] = Bs[tx * 4 + j][kk];
            #pragma unroll
            for (int i = 0; i < 4; ++i)
                #pragma unroll
                for (int j = 0; j < 4; ++j)
                    acc[i][j] += a[i] * bb[j];
        }
    }
    #pragma unroll
    for (int i = 0; i < 4; ++i) {
        int n = n0 + ty * 4 + i;
        #pragma unroll
        for (int j = 0; j < 4; ++j) {
            int o = o0 + tx * 4 + j;
            int part = o >> 9;
            int rr = o & 511;
            int h = rr >> 6, d = rr & 63;
            size_t dst = (((size_t)b * 8 + h) * 2048 + n) * 192 + d * 3 + c;
            float v = acc[i][j];
            if (part == 0)       Qb[dst] = v * SCALE;
            else if (part == 1)  Kb[dst] = v;
            else                 Vb[dst] = v;
        }
    }
}

// ---------------- K2: flash attention, fp32 ----------------
// grid (64 i-tiles, 16 bh), block 256 as 16x16 threads, each 2x2 of 32x32 S-tile
__global__ __launch_bounds__(256) void attn_fwd(const float* __restrict__ Qb,
                                                const float* __restrict__ Kb,
                                                const float* __restrict__ Vb,
                                                float* __restrict__ att) {
    __shared__ float q_s[32][196];
    __shared__ float k_s[32][196];
    __shared__ float v_s[32][196];
    __shared__ float p_s[32][33];
    const int bh = blockIdx.y;
    const int b = bh >> 3;
    const int h = bh & 7;
    const int i0 = blockIdx.x * 32;
    const int tid = threadIdx.x;
    const int ty = tid >> 4, tx = tid & 15;
    const float* Q = Qb + (size_t)bh * 2048 * 192;
    const float* K = Kb + (size_t)bh * 2048 * 192;
    const float* V = Vb + (size_t)bh * 2048 * 192;

    for (int idx = tid; idx < 32 * 192; idx += 256) {
        int r = idx / 192, cc = idx % 192;
        q_s[r][cc] = Q[(size_t)(i0 + r) * 192 + cc];
    }

    float m0 = -1e30f, m1 = -1e30f;
    float l0 = 0.f, l1 = 0.f;
    float o0[12] = {}, o1[12] = {};
    const int r0 = ty * 2;
    const int c0 = tx * 12;

    for (int jt = 0; jt < 64; ++jt) {
        const int j0 = jt * 32;
        __syncthreads();
        for (int idx = tid; idx < 32 * 192; idx += 256) {
            int r = idx / 192, cc = idx % 192;
            k_s[r][cc] = K[(size_t)(j0 + r) * 192 + cc];
            v_s[r][cc] = V[(size_t)(j0 + r) * 192 + cc];
        }
        __syncthreads();

        float s00 = 0, s01 = 0, s10 = 0, s11 = 0;
        #pragma unroll
        for (int k4 = 0; k4 < 48; ++k4) {
            float4 a0 = *(const float4*)&q_s[r0 + 0][k4 * 4];
            float4 a1 = *(const float4*)&q_s[r0 + 1][k4 * 4];
            float4 bb0 = *(const float4*)&k_s[tx * 2 + 0][k4 * 4];
            float4 bb1 = *(const float4*)&k_s[tx * 2 + 1][k4 * 4];
            s00 += a0.x * bb0.x + a0.y * bb0.y + a0.z * bb0.z + a0.w * bb0.w;
            s01 += a0.x * bb1.x + a0.y * bb1.y + a0.z * bb1.z + a0.w * bb1.w;
            s10 += a1.x * bb0.x + a1.y * bb0.y + a1.z * bb0.z + a1.w * bb0.w;
            s11 += a1.x * bb1.x + a1.y * bb1.y + a1.z * bb1.z + a1.w * bb1.w;
        }

        float rm0 = fmaxf(s00, s01), rm1 = fmaxf(s10, s11);
        #pragma unroll
        for (int msk = 1; msk < 16; msk <<= 1) {
            rm0 = fmaxf(rm0, __shfl_xor(rm0, msk, 64));
            rm1 = fmaxf(rm1, __shfl_xor(rm1, msk, 64));
        }
        float mn0 = fmaxf(m0, rm0), mn1 = fmaxf(m1, rm1);
        float sc0 = __expf(m0 - mn0), sc1 = __expf(m1 - mn1);
        float p00 = __expf(s00 - mn0), p01 = __expf(s01 - mn0);
        float p10 = __expf(s10 - mn1), p11 = __expf(s11 - mn1);
        float rs0 = p00 + p01, rs1 = p10 + p11;
        #pragma unroll
        for (int msk = 1; msk < 16; msk <<= 1) {
            rs0 += __shfl_xor(rs0, msk, 64);
            rs1 += __shfl_xor(rs1, msk, 64);
        }
        l0 = l0 * sc0 + rs0;
        l1 = l1 * sc1 + rs1;
        m0 = mn0; m1 = mn1;
        #pragma unroll
        for (int kk = 0; kk < 12; ++kk) { o0[kk] *= sc0; o1[kk] *= sc1; }
        p_s[r0 + 0][tx * 2 + 0] = p00;
        p_s[r0 + 0][tx * 2 + 1] = p01;
        p_s[r0 + 1][tx * 2 + 0] = p10;
        p_s[r0 + 1][tx * 2 + 1] = p11;
        __syncthreads();

        #pragma unroll 4
        for (int j = 0; j < 32; ++j) {
            float pv0 = p_s[r0 + 0][j];
            float pv1 = p_s[r0 + 1][j];
            const float* vr = &v_s[j][c0];
            float4 va = *(const float4*)(vr);
            float4 vb = *(const float4*)(vr + 4);
            float4 vc = *(const float4*)(vr + 8);
            o0[0] += pv0 * va.x;  o0[1] += pv0 * va.y;  o0[2]  += pv0 * va.z;  o0[3]  += pv0 * va.w;
            o0[4] += pv0 * vb.x;  o0[5] += pv0 * vb.y;  o0[6]  += pv0 * vb.z;  o0[7]  += pv0 * vb.w;
            o0[8] += pv0 * vc.x;  o0[9] += pv0 * vc.y;  o0[10] += pv0 * vc.z;  o0[11] += pv0 * vc.w;
            o1[0] += pv1 * va.x;  o1[1] += pv1 * va.y;  o1[2]  += pv1 * va.z;  o1[3]  += pv1 * va.w;
            o1[4] += pv1 * vb.x;  o1[5] += pv1 * vb.y;  o1[6]  += pv1 * vb.z;  o1[7]  += pv1 * vb.w;
            o1[8] += pv1 * vc.x;  o1[9] += pv1 * vc.y;  o1[10] += pv1 * vc.z;  o1[11] += pv1 * vc.w;
        }
    }

    float inv0 = 1.f / l0, inv1 = 1.f / l1;
    #pragma unroll
    for (int kk = 0; kk < 12; ++kk) {
        int dc = c0 + kk;
        int d = dc / 3, c = dc % 3;
        size_t base0 = (((size_t)b * 2048 + (i0 + r0 + 0)) * 512 + h * 64 + d) * 3 + c;
        size_t base1 = (((size_t)b * 2048 + (i0 + r0 + 1)) * 512 + h * 64 + d) * 3 + c;
        att[base0] = o0[kk] * inv0;
        att[base1] = o1[kk] * inv1;
    }
}

// ---------------- K3: output projection ----------------
// per (b,c): [2048,512] @ [512,256]^T -> out[b,n,o,c]
// grid (32 n-tiles, 4 o-tiles, 6 bc), block 256
__global__ __launch_bounds__(256) void out_proj(const float* __restrict__ att,
                                                const float* __restrict__ w_out,
                                                float* __restrict__ out) {
    __shared__ float As[64][17];
    __shared__ float Bs[64][17];
    const int bc = blockIdx.z;
    const int b = bc / 3, c = bc % 3;
    const int o0 = blockIdx.y * 64;
    const int n0 = blockIdx.x * 64;
    const int tid = threadIdx.x;
    const int ty = tid >> 4, tx = tid & 15;
    float acc[4][4] = {};
    for (int k0 = 0; k0 < 512; k0 += 16) {
        __syncthreads();
        #pragma unroll
        for (int l = 0; l < 4; ++l) {
            int idx = tid + l * 256;
            int r = idx >> 4, kk = idx & 15;
            As[r][kk] = att[(((size_t)b * 2048 + n0 + r) * 512 + k0 + kk) * 3 + c];
            Bs[r][kk] = w_out[(size_t)(o0 + r) * 512 + k0 + kk];
        }
        __syncthreads();
        #pragma unroll
        for (int kk = 0; kk < 16; ++kk) {
            float a[4], bb[4];
            #pragma unroll
            for (int i = 0; i < 4; ++i) a[i] = As[ty * 4 + i][kk];
            #pragma unroll
            for (int j = 0; j < 4; ++j) bb[j] = Bs[tx * 4 + j][kk];
            #pragma unroll
            for (int i = 0; i < 4; ++i)
                #pragma unroll
                for (int j = 0; j < 4; ++j)
                    acc[i][j] += a[i] * bb[j];
        }
    }
    #pragma unroll
    for (int i = 0; i < 4; ++i) {
        int n = n0 + ty * 4 + i;
        #pragma unroll
        for (int j = 0; j < 4; ++j) {
            int o = o0 + tx * 4 + j;
            out[(((size_t)b * 2048 + n) * 256 + o) * 3 + c] = acc[i][j];
        }
    }
}

extern "C" void kernel_launch(void* const* d_in, const int* in_sizes, int n_in,
                              void* d_out, int out_size, void* d_ws, size_t ws_size,
                              hipStream_t stream) {
    const float* x     = (const float*)d_in[0];
    const float* w_qkv = (const float*)d_in[1];
    const float* w_out = (const float*)d_in[2];
    float* out = (float*)d_out;

    const size_t SZ = (size_t)16 * 2048 * 192;  // 6.29M floats per buffer
    float* Qb  = (float*)d_ws;
    float* Kb  = Qb + SZ;
    float* Vb  = Kb + SZ;
    float* att = Vb + SZ;

    qkv_proj<<<dim3(32, 24, 6), 256, 0, stream>>>(x, w_qkv, Qb, Kb, Vb);
    attn_fwd<<<dim3(64, 16), 256, 0, stream>>>(Qb, Kb, Vb, att);
    out_proj<<<dim3(32, 4, 6), 256, 0, stream>>>(att, w_out, out);
}

// Round 2
// 501.245 us; speedup vs baseline: 3.0712x; 3.0712x over previous
//
#include <hip/hip_runtime.h>
#include <hip/hip_bf16.h>

#define SCALE 0.07216878364870322f  // (3*64)^-0.5

typedef __bf16 bf16x8 __attribute__((ext_vector_type(8)));
typedef float f32x16 __attribute__((ext_vector_type(16)));
typedef unsigned int u32x4 __attribute__((ext_vector_type(4)));

#define MFMA(a, b, c) __builtin_amdgcn_mfma_f32_32x32x16_bf16(a, b, c, 0, 0, 0)

__device__ __forceinline__ unsigned int pack2(float a, float b) {
    unsigned short ua = __builtin_bit_cast(unsigned short, (__bf16)a);
    unsigned short ub = __builtin_bit_cast(unsigned short, (__bf16)b);
    return (unsigned int)ua | ((unsigned int)ub << 16);
}

// ---------------- K1: QKV projection (fp32 GEMM, frag-major bf16 outputs) ----
// per (b,c): [2048,256] @ [256,1536]^T
// Q -> Qhi/Qlo  B-frag-major: [bh][it64][ks12][lane64][e8]
// K -> Khi/Klo  A-frag-major: [bh][jt32][jf2][ks12][lane64][e8]
// V -> Vf       A-frag-major (V^T): [bh][jt32][jk4][dcf6][lane64][e8]
__global__ __launch_bounds__(256) void qkv_proj(const float* __restrict__ x,
                                                const float* __restrict__ w_qkv,
                                                unsigned short* __restrict__ Qhi,
                                                unsigned short* __restrict__ Qlo,
                                                unsigned short* __restrict__ Khi,
                                                unsigned short* __restrict__ Klo,
                                                unsigned short* __restrict__ Vf) {
    __shared__ float As[64][17];
    __shared__ float Bs[64][17];
    const int bc = blockIdx.z;
    const int b = bc / 3, c = bc % 3;
    const int o0 = blockIdx.y * 64;
    const int n0 = blockIdx.x * 64;
    const int tid = threadIdx.x;
    const int ty = tid >> 4, tx = tid & 15;
    float acc[4][4] = {};
    for (int k0 = 0; k0 < 256; k0 += 16) {
        __syncthreads();
        #pragma unroll
        for (int l = 0; l < 4; ++l) {
            int idx = tid + l * 256;
            int r = idx >> 4, kk = idx & 15;
            As[r][kk] = x[(((size_t)b * 2048 + n0 + r) * 256 + k0 + kk) * 3 + c];
            Bs[r][kk] = w_qkv[(size_t)(o0 + r) * 256 + k0 + kk];
        }
        __syncthreads();
        #pragma unroll
        for (int kk = 0; kk < 16; ++kk) {
            float a[4], bb[4];
            #pragma unroll
            for (int i = 0; i < 4; ++i) a[i] = As[ty * 4 + i][kk];
            #pragma unroll
            for (int j = 0; j < 4; ++j) bb[j] = Bs[tx * 4 + j][kk];
            #pragma unroll
            for (int i = 0; i < 4; ++i)
                #pragma unroll
                for (int j = 0; j < 4; ++j)
                    acc[i][j] += a[i] * bb[j];
        }
    }
    #pragma unroll
    for (int i = 0; i < 4; ++i) {
        int n = n0 + ty * 4 + i;
        #pragma unroll
        for (int j = 0; j < 4; ++j) {
            int o = o0 + tx * 4 + j;
            float v = acc[i][j];
            int part = o >> 9;
            int oo = o & 511;
            int hh = oo >> 6, d = oo & 63;
            int dc = d * 3 + c;
            int bh = b * 8 + hh;
            if (part == 0) {
                float sv = v * SCALE;
                __bf16 hi = (__bf16)sv;
                __bf16 lo = (__bf16)(sv - (float)hi);
                int itq = n >> 5;
                int ln = (n & 31) | (((dc & 15) >> 3) << 5);
                int ks = dc >> 4, e = dc & 7;
                size_t off = ((((size_t)bh * 64 + itq) * 12 + ks) * 64 + ln) * 8 + e;
                Qhi[off] = __builtin_bit_cast(unsigned short, hi);
                Qlo[off] = __builtin_bit_cast(unsigned short, lo);
            } else if (part == 1) {
                __bf16 hi = (__bf16)v;
                __bf16 lo = (__bf16)(v - (float)hi);
                int jt = n >> 6, jf = (n >> 5) & 1;
                int ln = (n & 31) | (((dc & 15) >> 3) << 5);
                int ks = dc >> 4, e = dc & 7;
                size_t off = ((size_t)bh * 32 + jt) * 12288 +
                             (size_t)((jf * 12 + ks) * 64 + ln) * 8 + e;
                Khi[off] = __builtin_bit_cast(unsigned short, hi);
                Klo[off] = __builtin_bit_cast(unsigned short, lo);
            } else {
                __bf16 hv = (__bf16)v;
                int jt = n >> 6, jk = (n >> 4) & 3;
                int ln = (dc & 31) | (((n & 15) >> 3) << 5);
                int dcf = dc >> 5, e = n & 7;
                size_t off = ((size_t)bh * 32 + jt) * 12288 +
                             (size_t)((jk * 6 + dcf) * 64 + ln) * 8 + e;
                Vf[off] = __builtin_bit_cast(unsigned short, hv);
            }
        }
    }
}

// ---------------- K2: MFMA flash attention (swapped-operand, split-bf16 QK) --
// grid (16 itile-groups, 16 bh), block 256 (4 waves; wave = one 32-row i-group)
__global__ __launch_bounds__(256, 1) void attn_mfma(
    const unsigned short* __restrict__ Qhi, const unsigned short* __restrict__ Qlo,
    const unsigned short* __restrict__ Khi, const unsigned short* __restrict__ Klo,
    const unsigned short* __restrict__ Vf, float* __restrict__ att2) {
    __shared__ __align__(16) unsigned short lds[36864];  // K_hi | K_lo | V  (24.6KB each)
    const int tid = threadIdx.x;
    const int lane = tid & 63;
    const int w = tid >> 6;
    const int hf = lane >> 5;
    const int bh = blockIdx.y;
    const int itq = blockIdx.x * 4 + w;  // 32-row i-group

    // Q B-frags resident in registers (hi+lo)
    bf16x8 qh[12], ql[12];
    {
        size_t qb = (((size_t)bh * 64 + itq) * 12 * 64 + lane) * 8;
        #pragma unroll
        for (int ks = 0; ks < 12; ++ks) {
            qh[ks] = *(const bf16x8*)(Qhi + qb + ks * 512);
            ql[ks] = *(const bf16x8*)(Qlo + qb + ks * 512);
        }
    }

    const char* gK = (const char*)Khi + (size_t)bh * 786432;
    const char* gL = (const char*)Klo + (size_t)bh * 786432;
    const char* gV = (const char*)Vf + (size_t)bh * 786432;
    const int soff = w * 6144 + lane * 16;

    u32x4 tr[18];
    // prologue: stage jt=0
    #pragma unroll
    for (int cc = 0; cc < 6; ++cc) {
        tr[cc]      = *(const u32x4*)(gK + soff + cc * 1024);
        tr[6 + cc]  = *(const u32x4*)(gL + soff + cc * 1024);
        tr[12 + cc] = *(const u32x4*)(gV + soff + cc * 1024);
    }
    {
        char* lp = (char*)lds + soff;
        #pragma unroll
        for (int cc = 0; cc < 6; ++cc) {
            *(u32x4*)(lp + cc * 1024)         = tr[cc];
            *(u32x4*)(lp + 24576 + cc * 1024) = tr[6 + cc];
            *(u32x4*)(lp + 49152 + cc * 1024) = tr[12 + cc];
        }
    }
    __syncthreads();

    f32x16 o[6] = {};
    float m_run = -1e30f, l_run = 0.f;

    for (int jt = 0; jt < 32; ++jt) {
        // ---- S^T = K · Q^T (3-term split) ----
        f32x16 s00 = {}, s01 = {}, s10 = {}, s11 = {};
        #pragma unroll
        for (int mm = 0; mm < 6; ++mm) {
            const int k0 = mm * 2, k1 = mm * 2 + 1;
            bf16x8 kh00 = *(const bf16x8*)&lds[(size_t)((k0) * 64 + lane) * 8];
            bf16x8 kh01 = *(const bf16x8*)&lds[(size_t)((k1) * 64 + lane) * 8];
            bf16x8 kh10 = *(const bf16x8*)&lds[(size_t)((12 + k0) * 64 + lane) * 8];
            bf16x8 kh11 = *(const bf16x8*)&lds[(size_t)((12 + k1) * 64 + lane) * 8];
            bf16x8 kl00 = *(const bf16x8*)&lds[12288 + (size_t)((k0) * 64 + lane) * 8];
            bf16x8 kl01 = *(const bf16x8*)&lds[12288 + (size_t)((k1) * 64 + lane) * 8];
            bf16x8 kl10 = *(const bf16x8*)&lds[12288 + (size_t)((12 + k0) * 64 + lane) * 8];
            bf16x8 kl11 = *(const bf16x8*)&lds[12288 + (size_t)((12 + k1) * 64 + lane) * 8];
            s00 = MFMA(kh00, qh[k0], s00);
            s10 = MFMA(kh10, qh[k0], s10);
            s01 = MFMA(kh01, qh[k1], s01);
            s11 = MFMA(kh11, qh[k1], s11);
            s00 = MFMA(kh00, ql[k0], s00);
            s10 = MFMA(kh10, ql[k0], s10);
            s01 = MFMA(kh01, ql[k1], s01);
            s11 = MFMA(kh11, ql[k1], s11);
            s00 = MFMA(kl00, qh[k0], s00);
            s10 = MFMA(kl10, qh[k0], s10);
            s01 = MFMA(kl01, qh[k1], s01);
            s11 = MFMA(kl11, qh[k1], s11);
        }

        // ---- prefetch next K/V tile into regs (overlaps softmax + PV) ----
        if (jt + 1 < 32) {
            const size_t joff = (size_t)(jt + 1) * 24576 + soff;
            #pragma unroll
            for (int cc = 0; cc < 6; ++cc) {
                tr[cc]      = *(const u32x4*)(gK + joff + cc * 1024);
                tr[6 + cc]  = *(const u32x4*)(gL + joff + cc * 1024);
                tr[12 + cc] = *(const u32x4*)(gV + joff + cc * 1024);
            }
        }

        // ---- online softmax: lane-local rows (S^T) + one cross-half swap ----
        f32x16 sj0 = s00 + s01;
        f32x16 sj1 = s10 + s11;
        float rm = m_run;
        #pragma unroll
        for (int r = 0; r < 16; ++r) rm = fmaxf(rm, fmaxf(sj0[r], sj1[r]));
        rm = fmaxf(rm, __shfl_xor(rm, 32, 64));
        float sc = __expf(m_run - rm);
        float rs = 0.f;
        #pragma unroll
        for (int r = 0; r < 16; ++r) {
            sj0[r] = __expf(sj0[r] - rm); rs += sj0[r];
            sj1[r] = __expf(sj1[r] - rm); rs += sj1[r];
        }
        rs += __shfl_xor(rs, 32, 64);
        l_run = l_run * sc + rs;
        m_run = rm;
        #pragma unroll
        for (int d = 0; d < 6; ++d) o[d] = o[d] * sc;

        // ---- build P^T B-frags in registers (pack bf16 + half-swap shuffle) ----
        bf16x8 pf[4];
        {
            unsigned int pk[8], X[8];
            #pragma unroll
            for (int g = 0; g < 8; ++g) {
                pk[g] = pack2(sj0[2 * g], sj0[2 * g + 1]);
                X[g] = (unsigned int)__shfl_xor((int)pk[g], 32, 64);
            }
            u32x4 f0 = {hf ? X[2] : pk[0], hf ? X[3] : pk[1], hf ? pk[2] : X[0], hf ? pk[3] : X[1]};
            u32x4 f1 = {hf ? X[6] : pk[4], hf ? X[7] : pk[5], hf ? pk[6] : X[4], hf ? pk[7] : X[5]};
            pf[0] = __builtin_bit_cast(bf16x8, f0);
            pf[1] = __builtin_bit_cast(bf16x8, f1);
            #pragma unroll
            for (int g = 0; g < 8; ++g) {
                pk[g] = pack2(sj1[2 * g], sj1[2 * g + 1]);
                X[g] = (unsigned int)__shfl_xor((int)pk[g], 32, 64);
            }
            u32x4 f2 = {hf ? X[2] : pk[0], hf ? X[3] : pk[1], hf ? pk[2] : X[0], hf ? pk[3] : X[1]};
            u32x4 f3 = {hf ? X[6] : pk[4], hf ? X[7] : pk[5], hf ? pk[6] : X[4], hf ? pk[7] : X[5]};
            pf[2] = __builtin_bit_cast(bf16x8, f2);
            pf[3] = __builtin_bit_cast(bf16x8, f3);
        }

        // ---- O^T += V^T · P^T ----
        #pragma unroll
        for (int jk = 0; jk < 4; ++jk) {
            #pragma unroll
            for (int d = 0; d < 6; ++d) {
                bf16x8 vf = *(const bf16x8*)&lds[24576 + (size_t)((jk * 6 + d) * 64 + lane) * 8];
                o[d] = MFMA(vf, pf[jk], o[d]);
            }
        }

        // ---- write staged regs -> LDS for next tile ----
        if (jt + 1 < 32) {
            __syncthreads();
            char* lp = (char*)lds + soff;
            #pragma unroll
            for (int cc = 0; cc < 6; ++cc) {
                *(u32x4*)(lp + cc * 1024)         = tr[cc];
                *(u32x4*)(lp + 24576 + cc * 1024) = tr[6 + cc];
                *(u32x4*)(lp + 49152 + cc * 1024) = tr[12 + cc];
            }
            __syncthreads();
        }
    }

    // ---- epilogue: att2[bh][dc][n] = O^T / l ----
    float inv = 1.0f / l_run;
    const int i = itq * 32 + (lane & 31);
    #pragma unroll
    for (int d = 0; d < 6; ++d) {
        #pragma unroll
        for (int r = 0; r < 16; ++r) {
            int dc = d * 32 + (r & 3) + 8 * (r >> 2) + 4 * hf;
            att2[((size_t)bh * 192 + dc) * 2048 + i] = o[d][r] * inv;
        }
    }
}

// ---------------- K3: output projection (fp32) ----------------
// per (b,c): [2048,512] @ [512,256]^T -> out[b,n,o,c]; att2 is [bh][dc][n]
__global__ __launch_bounds__(256) void out_proj(const float* __restrict__ att2,
                                                const float* __restrict__ w_out,
                                                float* __restrict__ out) {
    __shared__ float As[64][17];
    __shared__ float Bs[64][17];
    const int bc = blockIdx.z;
    const int b = bc / 3, c = bc % 3;
    const int o0 = blockIdx.y * 64;
    const int n0 = blockIdx.x * 64;
    const int tid = threadIdx.x;
    const int ty = tid >> 4, tx = tid & 15;
    float acc[4][4] = {};
    for (int k0 = 0; k0 < 512; k0 += 16) {
        __syncthreads();
        #pragma unroll
        for (int p = 0; p < 4; ++p) {
            int r = tid & 63;
            int kk = (tid >> 6) + p * 4;
            int o512 = k0 + kk;
            int hh = o512 >> 6, d = o512 & 63;
            As[r][kk] = att2[(((size_t)b * 8 + hh) * 192 + d * 3 + c) * 2048 + n0 + r];
        }
        #pragma unroll
        for (int l = 0; l < 4; ++l) {
            int idx = tid + l * 256;
            int r = idx >> 4, kk = idx & 15;
            Bs[r][kk] = w_out[(size_t)(o0 + r) * 512 + k0 + kk];
        }
        __syncthreads();
        #pragma unroll
        for (int kk = 0; kk < 16; ++kk) {
            float a[4], bb[4];
            #pragma unroll
            for (int i = 0; i < 4; ++i) a[i] = As[ty * 4 + i][kk];
            #pragma unroll
            for (int j = 0; j < 4; ++j) bb[j] = Bs[tx * 4 + j][kk];
            #pragma unroll
            for (int i = 0; i < 4; ++i)
                #pragma unroll
                for (int j = 0; j < 4; ++j)
                    acc[i][j] += a[i] * bb[j];
        }
    }
    #pragma unroll
    for (int i = 0; i < 4; ++i) {
        int n = n0 + ty * 4 + i;
        #pragma unroll
        for (int j = 0; j < 4; ++j) {
            int o = o0 + tx * 4 + j;
            out[(((size_t)b * 2048 + n) * 256 + o) * 3 + c] = acc[i][j];
        }
    }
}

extern "C" void kernel_launch(void* const* d_in, const int* in_sizes, int n_in,
                              void* d_out, int out_size, void* d_ws, size_t ws_size,
                              hipStream_t stream) {
    const float* x     = (const float*)d_in[0];
    const float* w_qkv = (const float*)d_in[1];
    const float* w_out = (const float*)d_in[2];
    float* out = (float*)d_out;

    const size_t NB = (size_t)16 * 2048 * 192;  // 6.29M elements per buffer
    unsigned short* Qhi = (unsigned short*)d_ws;
    unsigned short* Qlo = Qhi + NB;
    unsigned short* Khi = Qlo + NB;
    unsigned short* Klo = Khi + NB;
    unsigned short* Vf  = Klo + NB;
    float* att2 = (float*)(Vf + NB);

    qkv_proj<<<dim3(32, 24, 6), 256, 0, stream>>>(x, w_qkv, Qhi, Qlo, Khi, Klo, Vf);
    attn_mfma<<<dim3(16, 16), 256, 0, stream>>>(Qhi, Qlo, Khi, Klo, Vf, att2);
    out_proj<<<dim3(32, 4, 6), 256, 0, stream>>>(att2, w_out, out);
}

// Round 3
// 251.795 us; speedup vs baseline: 6.1139x; 1.9907x over previous
//
#include <hip/hip_runtime.h>
#include <hip/hip_bf16.h>

#define SCALE 0.07216878364870322f  // (3*64)^-0.5

typedef __bf16 bf16x8 __attribute__((ext_vector_type(8)));
typedef float f32x16 __attribute__((ext_vector_type(16)));
typedef float f32x4v __attribute__((ext_vector_type(4)));
typedef unsigned int u32x4 __attribute__((ext_vector_type(4)));
typedef unsigned short u16;

#define MFMA(a, b, c) __builtin_amdgcn_mfma_f32_32x32x16_bf16(a, b, c, 0, 0, 0)

__device__ __forceinline__ u16 b16(float v) { return __builtin_bit_cast(u16, (__bf16)v); }
__device__ __forceinline__ float fb16(u16 u) {
    unsigned int t = (unsigned int)u << 16;
    return __builtin_bit_cast(float, t);
}
// pack hi|lo<<16 bf16 split of v
__device__ __forceinline__ unsigned int splitpack(float v) {
    u16 h = b16(v);
    float r = v - fb16(h);
    return (unsigned int)h | ((unsigned int)b16(r) << 16);
}
__device__ __forceinline__ unsigned int pack2(float a, float b) {
    return (unsigned int)b16(a) | ((unsigned int)b16(b) << 16);
}

// ---------------- K1: QKV projection, MFMA split-bf16, zero-LDS main loop ----
// grid (24 o-tiles of 64, 16 n-tiles of 128, 2 b), block 256 (4 waves, wave = 32 n-rows)
// Outputs (frag-major, consumed by attn_mfma):
//  Q/K hi+lo: off = bh*393216 + ((n>>5)*12 + ks)*512 + ((n&31)|(((dc>>3)&1)<<5))*8 + (dc&7)
//  V:         off = bh*393216 + (n>>6)*12288 + ((((n>>4)&3)*6 + (dc>>5))*64 + ((dc&31)|(((n>>3)&1)<<5)))*8 + (n&7)
__global__ __launch_bounds__(256) void qkv_mfma(const float* __restrict__ x,
                                                const float* __restrict__ wq,
                                                u16* __restrict__ Qhi, u16* __restrict__ Qlo,
                                                u16* __restrict__ Khi, u16* __restrict__ Klo,
                                                u16* __restrict__ Vf) {
    __shared__ unsigned int ldsr[2][32][196];  // repack tiles, 2 waves at a time
    const int tid = threadIdx.x;
    const int lane = tid & 63, w = tid >> 6, hf = lane >> 5, l31 = lane & 31;
    const int o0 = blockIdx.x * 64;
    const int n0 = blockIdx.y * 128;
    const int b = blockIdx.z;
    const int nw0 = n0 + w * 32;
    const int part = o0 >> 9;
    const int h = (o0 >> 6) & 7;
    const int bh = b * 8 + h;

    // A-frag source: x[b][nw0+l31][i = k0*16 + hf*8 + e][c] -> 24 contiguous floats
    const float* xp = x + ((size_t)(b * 2048 + nw0 + l31)) * 768 + hf * 24;
    // B-frag source: wq[o0 + ot*32 + l31][k0*16 + hf*8 + e]
    const float* wp0 = wq + (size_t)(o0 + l31) * 256 + hf * 8;
    const float* wp1 = wp0 + 32 * 256;

    f32x16 acc[3][2] = {};
    #pragma unroll 2
    for (int k0 = 0; k0 < 16; ++k0) {
        float xf[24], wf0[8], wf1[8];
        #pragma unroll
        for (int q = 0; q < 6; ++q) {
            f32x4v t = *(const f32x4v*)(xp + k0 * 48 + q * 4);
            xf[q * 4 + 0] = t[0]; xf[q * 4 + 1] = t[1];
            xf[q * 4 + 2] = t[2]; xf[q * 4 + 3] = t[3];
        }
        {
            f32x4v t0 = *(const f32x4v*)(wp0 + k0 * 16);
            f32x4v t1 = *(const f32x4v*)(wp0 + k0 * 16 + 4);
            f32x4v t2 = *(const f32x4v*)(wp1 + k0 * 16);
            f32x4v t3 = *(const f32x4v*)(wp1 + k0 * 16 + 4);
            #pragma unroll
            for (int e = 0; e < 4; ++e) {
                wf0[e] = t0[e]; wf0[4 + e] = t1[e];
                wf1[e] = t2[e]; wf1[4 + e] = t3[e];
            }
        }
        bf16x8 xh[3], xl[3], wh[2], wl[2];
        #pragma unroll
        for (int c = 0; c < 3; ++c)
            #pragma unroll
            for (int e = 0; e < 8; ++e) {
                float v = xf[e * 3 + c];
                __bf16 hi = (__bf16)v;
                xh[c][e] = hi;
                xl[c][e] = (__bf16)(v - (float)hi);
            }
        #pragma unroll
        for (int e = 0; e < 8; ++e) {
            { float v = wf0[e]; __bf16 hi = (__bf16)v; wh[0][e] = hi; wl[0][e] = (__bf16)(v - (float)hi); }
            { float v = wf1[e]; __bf16 hi = (__bf16)v; wh[1][e] = hi; wl[1][e] = (__bf16)(v - (float)hi); }
        }
        #pragma unroll
        for (int c = 0; c < 3; ++c)
            #pragma unroll
            for (int ot = 0; ot < 2; ++ot) {
                acc[c][ot] = MFMA(xh[c], wh[ot], acc[c][ot]);
                acc[c][ot] = MFMA(xl[c], wh[ot], acc[c][ot]);
                acc[c][ot] = MFMA(xh[c], wl[ot], acc[c][ot]);
            }
    }

    // ---- epilogue: repack C (n x 192dc) through LDS into frag-major layouts ----
    #pragma unroll
    for (int round = 0; round < 2; ++round) {
        __syncthreads();
        if ((w >> 1) == round) {
            unsigned int (*L)[196] = ldsr[w & 1];
            #pragma unroll
            for (int c = 0; c < 3; ++c)
                #pragma unroll
                for (int ot = 0; ot < 2; ++ot)
                    #pragma unroll
                    for (int r = 0; r < 16; ++r) {
                        float v = acc[c][ot][r];
                        if (part == 0) v *= SCALE;
                        int nn = (r & 3) + 8 * (r >> 2) + 4 * hf;
                        int dcol = 3 * (ot * 32 + l31) + c;
                        L[nn][dcol] = (part == 2) ? (unsigned int)b16(v) : splitpack(v);
                    }
            if (part < 2) {
                const int itqw = blockIdx.y * 4 + w;
                u16* bhp = (part == 0 ? Qhi : Khi) + (size_t)bh * 393216 + itqw * 6144 + lane * 8;
                u16* blp = (part == 0 ? Qlo : Klo) + (size_t)bh * 393216 + itqw * 6144 + lane * 8;
                #pragma unroll
                for (int ks = 0; ks < 12; ++ks) {
                    const unsigned int* p = &L[l31][ks * 16 + hf * 8];
                    u32x4 a = *(const u32x4*)p;
                    u32x4 bq = *(const u32x4*)(p + 4);
                    u32x4 hi = { (a[0] & 0xffffu) | (a[1] << 16), (a[2] & 0xffffu) | (a[3] << 16),
                                 (bq[0] & 0xffffu) | (bq[1] << 16), (bq[2] & 0xffffu) | (bq[3] << 16) };
                    u32x4 lo = { (a[0] >> 16) | (a[1] & 0xffff0000u), (a[2] >> 16) | (a[3] & 0xffff0000u),
                                 (bq[0] >> 16) | (bq[1] & 0xffff0000u), (bq[2] >> 16) | (bq[3] & 0xffff0000u) };
                    *(u32x4*)(bhp + ks * 512) = hi;
                    *(u32x4*)(blp + ks * 512) = lo;
                }
            } else {
                const int jt = nw0 >> 6;
                u16* vp = Vf + (size_t)bh * 393216 + jt * 12288 + lane * 8;
                #pragma unroll
                for (int jkk = 0; jkk < 2; ++jkk) {
                    const int jk = ((nw0 >> 4) + jkk) & 3;
                    #pragma unroll
                    for (int dcf = 0; dcf < 6; ++dcf) {
                        unsigned int t[8];
                        #pragma unroll
                        for (int e = 0; e < 8; ++e)
                            t[e] = L[jkk * 16 + hf * 8 + e][dcf * 32 + l31];
                        u32x4 pk = { (t[0] & 0xffffu) | (t[1] << 16), (t[2] & 0xffffu) | (t[3] << 16),
                                     (t[4] & 0xffffu) | (t[5] << 16), (t[6] & 0xffffu) | (t[7] << 16) };
                        *(u32x4*)(vp + (jk * 6 + dcf) * 512) = pk;
                    }
                }
            }
        }
    }
}

// ---------------- K2: MFMA flash attention (swapped-operand, split-bf16 QK) --
// grid (16 itile-groups, 16 bh), block 256 (4 waves; wave = one 32-row i-group)
__global__ __launch_bounds__(256, 1) void attn_mfma(
    const u16* __restrict__ Qhi, const u16* __restrict__ Qlo,
    const u16* __restrict__ Khi, const u16* __restrict__ Klo,
    const u16* __restrict__ Vf, unsigned int* __restrict__ att2) {
    __shared__ __align__(16) u16 lds[36864];  // K_hi | K_lo | V
    const int tid = threadIdx.x;
    const int lane = tid & 63;
    const int w = tid >> 6;
    const int hf = lane >> 5;
    const int bh = blockIdx.y;
    const int itq = blockIdx.x * 4 + w;

    bf16x8 qh[12], ql[12];
    {
        size_t qb = (((size_t)bh * 64 + itq) * 12 * 64 + lane) * 8;
        #pragma unroll
        for (int ks = 0; ks < 12; ++ks) {
            qh[ks] = *(const bf16x8*)(Qhi + qb + ks * 512);
            ql[ks] = *(const bf16x8*)(Qlo + qb + ks * 512);
        }
    }

    const char* gK = (const char*)Khi + (size_t)bh * 786432;
    const char* gL = (const char*)Klo + (size_t)bh * 786432;
    const char* gV = (const char*)Vf + (size_t)bh * 786432;
    const int soff = w * 6144 + lane * 16;

    u32x4 tr[18];
    #pragma unroll
    for (int cc = 0; cc < 6; ++cc) {
        tr[cc]      = *(const u32x4*)(gK + soff + cc * 1024);
        tr[6 + cc]  = *(const u32x4*)(gL + soff + cc * 1024);
        tr[12 + cc] = *(const u32x4*)(gV + soff + cc * 1024);
    }
    {
        char* lp = (char*)lds + soff;
        #pragma unroll
        for (int cc = 0; cc < 6; ++cc) {
            *(u32x4*)(lp + cc * 1024)         = tr[cc];
            *(u32x4*)(lp + 24576 + cc * 1024) = tr[6 + cc];
            *(u32x4*)(lp + 49152 + cc * 1024) = tr[12 + cc];
        }
    }
    __syncthreads();

    f32x16 o[6] = {};
    float m_run = -1e30f, l_run = 0.f;

    for (int jt = 0; jt < 32; ++jt) {
        f32x16 s00 = {}, s01 = {}, s10 = {}, s11 = {};
        #pragma unroll
        for (int mm = 0; mm < 6; ++mm) {
            const int k0 = mm * 2, k1 = mm * 2 + 1;
            bf16x8 kh00 = *(const bf16x8*)&lds[(size_t)((k0) * 64 + lane) * 8];
            bf16x8 kh01 = *(const bf16x8*)&lds[(size_t)((k1) * 64 + lane) * 8];
            bf16x8 kh10 = *(const bf16x8*)&lds[(size_t)((12 + k0) * 64 + lane) * 8];
            bf16x8 kh11 = *(const bf16x8*)&lds[(size_t)((12 + k1) * 64 + lane) * 8];
            bf16x8 kl00 = *(const bf16x8*)&lds[12288 + (size_t)((k0) * 64 + lane) * 8];
            bf16x8 kl01 = *(const bf16x8*)&lds[12288 + (size_t)((k1) * 64 + lane) * 8];
            bf16x8 kl10 = *(const bf16x8*)&lds[12288 + (size_t)((12 + k0) * 64 + lane) * 8];
            bf16x8 kl11 = *(const bf16x8*)&lds[12288 + (size_t)((12 + k1) * 64 + lane) * 8];
            s00 = MFMA(kh00, qh[k0], s00);
            s10 = MFMA(kh10, qh[k0], s10);
            s01 = MFMA(kh01, qh[k1], s01);
            s11 = MFMA(kh11, qh[k1], s11);
            s00 = MFMA(kh00, ql[k0], s00);
            s10 = MFMA(kh10, ql[k0], s10);
            s01 = MFMA(kh01, ql[k1], s01);
            s11 = MFMA(kh11, ql[k1], s11);
            s00 = MFMA(kl00, qh[k0], s00);
            s10 = MFMA(kl10, qh[k0], s10);
            s01 = MFMA(kl01, qh[k1], s01);
            s11 = MFMA(kl11, qh[k1], s11);
        }

        if (jt + 1 < 32) {
            const size_t joff = (size_t)(jt + 1) * 24576 + soff;
            #pragma unroll
            for (int cc = 0; cc < 6; ++cc) {
                tr[cc]      = *(const u32x4*)(gK + joff + cc * 1024);
                tr[6 + cc]  = *(const u32x4*)(gL + joff + cc * 1024);
                tr[12 + cc] = *(const u32x4*)(gV + joff + cc * 1024);
            }
        }

        f32x16 sj0 = s00 + s01;
        f32x16 sj1 = s10 + s11;
        float rm = m_run;
        #pragma unroll
        for (int r = 0; r < 16; ++r) rm = fmaxf(rm, fmaxf(sj0[r], sj1[r]));
        rm = fmaxf(rm, __shfl_xor(rm, 32, 64));
        float sc = __expf(m_run - rm);
        float rs = 0.f;
        #pragma unroll
        for (int r = 0; r < 16; ++r) {
            sj0[r] = __expf(sj0[r] - rm); rs += sj0[r];
            sj1[r] = __expf(sj1[r] - rm); rs += sj1[r];
        }
        rs += __shfl_xor(rs, 32, 64);
        l_run = l_run * sc + rs;
        m_run = rm;
        #pragma unroll
        for (int d = 0; d < 6; ++d) o[d] = o[d] * sc;

        bf16x8 pf[4];
        {
            unsigned int pk[8], X[8];
            #pragma unroll
            for (int g = 0; g < 8; ++g) {
                pk[g] = pack2(sj0[2 * g], sj0[2 * g + 1]);
                X[g] = (unsigned int)__shfl_xor((int)pk[g], 32, 64);
            }
            u32x4 f0 = {hf ? X[2] : pk[0], hf ? X[3] : pk[1], hf ? pk[2] : X[0], hf ? pk[3] : X[1]};
            u32x4 f1 = {hf ? X[6] : pk[4], hf ? X[7] : pk[5], hf ? pk[6] : X[4], hf ? pk[7] : X[5]};
            pf[0] = __builtin_bit_cast(bf16x8, f0);
            pf[1] = __builtin_bit_cast(bf16x8, f1);
            #pragma unroll
            for (int g = 0; g < 8; ++g) {
                pk[g] = pack2(sj1[2 * g], sj1[2 * g + 1]);
                X[g] = (unsigned int)__shfl_xor((int)pk[g], 32, 64);
            }
            u32x4 f2 = {hf ? X[2] : pk[0], hf ? X[3] : pk[1], hf ? pk[2] : X[0], hf ? pk[3] : X[1]};
            u32x4 f3 = {hf ? X[6] : pk[4], hf ? X[7] : pk[5], hf ? pk[6] : X[4], hf ? pk[7] : X[5]};
            pf[2] = __builtin_bit_cast(bf16x8, f2);
            pf[3] = __builtin_bit_cast(bf16x8, f3);
        }

        #pragma unroll
        for (int jk = 0; jk < 4; ++jk)
            #pragma unroll
            for (int d = 0; d < 6; ++d) {
                bf16x8 vf = *(const bf16x8*)&lds[24576 + (size_t)((jk * 6 + d) * 64 + lane) * 8];
                o[d] = MFMA(vf, pf[jk], o[d]);
            }

        if (jt + 1 < 32) {
            __syncthreads();
            char* lp = (char*)lds + soff;
            #pragma unroll
            for (int cc = 0; cc < 6; ++cc) {
                *(u32x4*)(lp + cc * 1024)         = tr[cc];
                *(u32x4*)(lp + 24576 + cc * 1024) = tr[6 + cc];
                *(u32x4*)(lp + 49152 + cc * 1024) = tr[12 + cc];
            }
            __syncthreads();
        }
    }

    // epilogue: att2 (A-frag-major for out_proj) = pack(hi,lo) of O/l
    float inv = 1.0f / l_run;
    const int b2 = bh >> 3, hh = bh & 7;
    const int i31 = lane & 31;
    #pragma unroll
    for (int d = 0; d < 6; ++d)
        #pragma unroll
        for (int r = 0; r < 16; ++r) {
            int dc = d * 32 + (r & 3) + 8 * (r >> 2) + 4 * hf;
            int dd = dc / 3, cc = dc - dd * 3;
            int hd = hh * 64 + dd;
            int ks = hd >> 4, e = hd & 7;
            int ln = i31 | (((hd >> 3) & 1) << 5);
            size_t off = ((((size_t)(b2 * 3 + cc) * 32 + ks) * 64 + itq) * 512 + (size_t)ln * 8 + e);
            float v = o[d][r] * inv;
            att2[off] = splitpack(v);
        }
}

// ---------------- K3: output projection, MFMA split-bf16, no LDS ----------------
// grid (8 o-tiles of 32, 16 n-tiles of 128, 2 b), block 256 (4 independent waves)
__global__ __launch_bounds__(256) void out_mfma(const unsigned int* __restrict__ att2,
                                                const float* __restrict__ wo,
                                                float* __restrict__ out) {
    const int tid = threadIdx.x, lane = tid & 63, w = tid >> 6, hf = lane >> 5, l31 = lane & 31;
    const int o0 = blockIdx.x * 32;
    const int n5 = blockIdx.y * 4 + w;
    const int b = blockIdx.z;
    const float* wp = wo + (size_t)(o0 + l31) * 512 + hf * 8;
    const unsigned int* ap = att2 + ((size_t)(b * 3) * 2048 + n5) * 512 + (size_t)lane * 8;
    f32x16 acc[3] = {};
    #pragma unroll 2
    for (int ks = 0; ks < 32; ++ks) {
        bf16x8 wh, wl;
        {
            f32x4v t0 = *(const f32x4v*)(wp + ks * 16);
            f32x4v t1 = *(const f32x4v*)(wp + ks * 16 + 4);
            #pragma unroll
            for (int e = 0; e < 4; ++e) {
                { float v = t0[e]; __bf16 hi = (__bf16)v; wh[e] = hi; wl[e] = (__bf16)(v - (float)hi); }
                { float v = t1[e]; __bf16 hi = (__bf16)v; wh[4 + e] = hi; wl[4 + e] = (__bf16)(v - (float)hi); }
            }
        }
        #pragma unroll
        for (int c = 0; c < 3; ++c) {
            const unsigned int* pc = ap + (size_t)c * 1048576 + ks * 32768;
            u32x4 a0 = *(const u32x4*)pc;
            u32x4 a1 = *(const u32x4*)(pc + 4);
            union { bf16x8 v; u32x4 u; } H, Lo;
            H.u  = { (a0[0] & 0xffffu) | (a0[1] << 16), (a0[2] & 0xffffu) | (a0[3] << 16),
                     (a1[0] & 0xffffu) | (a1[1] << 16), (a1[2] & 0xffffu) | (a1[3] << 16) };
            Lo.u = { (a0[0] >> 16) | (a0[1] & 0xffff0000u), (a0[2] >> 16) | (a0[3] & 0xffff0000u),
                     (a1[0] >> 16) | (a1[1] & 0xffff0000u), (a1[2] >> 16) | (a1[3] & 0xffff0000u) };
            acc[c] = MFMA(H.v, wh, acc[c]);
            acc[c] = MFMA(Lo.v, wh, acc[c]);
            acc[c] = MFMA(H.v, wl, acc[c]);
        }
    }
    #pragma unroll
    for (int r = 0; r < 16; ++r) {
        int n = (n5 << 5) + (r & 3) + 8 * (r >> 2) + 4 * hf;
        size_t off = ((size_t)(b * 2048 + n) * 256 + o0 + l31) * 3;
        out[off]     = acc[0][r];
        out[off + 1] = acc[1][r];
        out[off + 2] = acc[2][r];
    }
}

extern "C" void kernel_launch(void* const* d_in, const int* in_sizes, int n_in,
                              void* d_out, int out_size, void* d_ws, size_t ws_size,
                              hipStream_t stream) {
    const float* x     = (const float*)d_in[0];
    const float* w_qkv = (const float*)d_in[1];
    const float* w_out = (const float*)d_in[2];
    float* out = (float*)d_out;

    const size_t NB = (size_t)16 * 2048 * 192;  // 6.29M elements per buffer
    u16* Qhi = (u16*)d_ws;
    u16* Qlo = Qhi + NB;
    u16* Khi = Qlo + NB;
    u16* Klo = Khi + NB;
    u16* Vf  = Klo + NB;
    unsigned int* att2 = (unsigned int*)(Vf + NB);

    qkv_mfma<<<dim3(24, 16, 2), 256, 0, stream>>>(x, w_qkv, Qhi, Qlo, Khi, Klo, Vf);
    attn_mfma<<<dim3(16, 16), 256, 0, stream>>>(Qhi, Qlo, Khi, Klo, Vf, att2);
    out_mfma<<<dim3(8, 16, 2), 256, 0, stream>>>(att2, w_out, out);
}